// Round 9
// baseline (144.255 us; speedup 1.0000x reference)
//
#include <hip/hip_runtime.h>
#include <math.h>

#define SEQ 130
#define SPAD 144      // 9 tiles of 16
#define EMB 16
#define LIN 1039
#define LPAD 1040
#define FP 20         // f16 row pad (halves) for hF/kF/winF/woutF
#define VTP 152       // vT row pad (halves): 304B rows keep 8B-aligned b64 frags

typedef __attribute__((ext_vector_type(4))) _Float16 half4v;
typedef __attribute__((ext_vector_type(4))) float float4v;

// ---- posenc (+ b_proj folded) table: computed once per launch into d_ws ----
__global__ void pe_kernel(const float* __restrict__ b_proj, float2* __restrict__ pe) {
    int idx = blockIdx.x * 256 + threadIdx.x;
    if (idx < SEQ * 8) {
        int s = idx >> 3, i = idx & 7;
        float div = expf(-(float)(2 * i) * 0.57564627324851149f); // ln(1e4)/16
        float ang = (float)s * div;
        pe[idx] = make_float2(sinf(ang) + b_proj[2 * i],
                              cosf(ang) + b_proj[2 * i + 1]);
    }
}

// 192 threads = 3 waves; wave wv owns q-tiles {3wv, 3wv+1, 3wv+2} (9 tiles).
__global__ __launch_bounds__(192) void st_kernel(
    const float* __restrict__ x,
    const float* __restrict__ w_proj,
    const float* __restrict__ w_in,  const float* __restrict__ b_in,
    const float* __restrict__ w_out, const float* __restrict__ b_out,
    const float* __restrict__ ln1_g, const float* __restrict__ ln1_b,
    const float* __restrict__ w1,    const float* __restrict__ b1,
    const float* __restrict__ w2,    const float* __restrict__ b2,
    const float* __restrict__ ln2_g, const float* __restrict__ ln2_b,
    const float2* __restrict__ pe,
    float* __restrict__ out)
{
    __shared__ __align__(16) float xs[LPAD];
    __shared__ __align__(8) _Float16 hF[SPAD][FP];
    __shared__ __align__(8) _Float16 kF[SPAD][FP];
    __shared__ __align__(16) _Float16 vT[EMB][VTP];   // V transposed: vT[e][k]
    __shared__ __align__(8) _Float16 winF[48][FP];
    __shared__ __align__(8) _Float16 woutF[16][FP];
    __shared__ float wprojS[EMB][9];
    __shared__ __align__(16) float binS[48];
    __shared__ __align__(16) float boutS[16], w1S[16], w2S[16], b2S[16];
    __shared__ __align__(16) float ln1gS[16], ln1bS[16], ln2gS[16], ln2bS[16];
    __shared__ float b1S;
    __shared__ float psum[3][16];

    const int tid = threadIdx.x;
    const int b   = blockIdx.x;

    // ---- stage parameters ----
    if (tid < 128) wprojS[tid >> 3][tid & 7] = w_proj[tid];
    for (int i = tid; i < 384; i += 192) {          // w_in -> f16 (q rows ×0.25)
        int f = i >> 3, ep = i & 7;
        float sc = (f < 16) ? 0.25f : 1.0f;
        union { _Float16 h[2]; unsigned u; } pk;
        pk.h[0] = (_Float16)(w_in[f * 16 + 2 * ep] * sc);
        pk.h[1] = (_Float16)(w_in[f * 16 + 2 * ep + 1] * sc);
        *(unsigned*)&winF[f][2 * ep] = pk.u;
    }
    if (tid < 128) {                                 // w_out -> f16
        int f = tid >> 3, ep = tid & 7;
        union { _Float16 h[2]; unsigned u; } pk;
        pk.h[0] = (_Float16)w_out[f * 16 + 2 * ep];
        pk.h[1] = (_Float16)w_out[f * 16 + 2 * ep + 1];
        *(unsigned*)&woutF[f][2 * ep] = pk.u;
    }
    if (tid < 48) binS[tid] = b_in[tid] * ((tid < 16) ? 0.25f : 1.0f);
    if (tid >= 128 && tid < 144) {
        int e = tid - 128;
        boutS[e] = b_out[e]; w1S[e] = w1[e]; w2S[e] = w2[e]; b2S[e] = b2[e];
    }
    if (tid >= 144 && tid < 160) {
        int e = tid - 144;
        ln1gS[e] = ln1_g[e]; ln1bS[e] = ln1_b[e];
        ln2gS[e] = ln2_g[e]; ln2bS[e] = ln2_b[e];
    }
    if (tid == 160) b1S = b1[0];
    if (tid < 140) {                                 // zero hF pad rows 130..143
        int r = SEQ + tid / 10, w = tid % 10;
        *(unsigned*)&hF[r][2 * w] = 0u;
    }
    const float* xrow = x + (size_t)b * LIN;
    for (int i = tid; i < LPAD; i += 192) xs[i] = (i < LIN) ? xrow[i] : 0.0f;
    __syncthreads();

    // ---- phase 1: h = patches @ w_proj^T + (posenc + b_proj) -> f16 ----
    for (int idx = tid; idx < SEQ * 8; idx += 192) {
        int s = idx >> 3, i = idx & 7;
        const float* xp = &xs[s * 8];
        float a0 = 0.f, a1 = 0.f;
        #pragma unroll
        for (int p = 0; p < 8; ++p) {
            float xv = xp[p];
            a0 += xv * wprojS[2 * i][p];
            a1 += xv * wprojS[2 * i + 1][p];
        }
        float2 pp = pe[idx];
        a0 += pp.x; a1 += pp.y;
        union { _Float16 h[2]; unsigned u; } pk;
        pk.h[0] = (_Float16)a0; pk.h[1] = (_Float16)a1;
        *(unsigned*)&hF[s][2 * i] = pk.u;
    }
    __syncthreads();

    // ---- lane geometry ----
    const int lane = tid & 63;
    const int wv   = tid >> 6;          // 0..2
    const int c    = lane & 15;
    const int g    = lane >> 4;
    const float4v zero4 = {0.f, 0.f, 0.f, 0.f};

    // ---- phase 2: qkv via MFMA; q stays in regs, k -> kF, v -> vT ----
    half4v qf[3], hfr[3];
    {
        const half4v wq = *(const half4v*)&winF[c][4 * g];
        const half4v wk = *(const half4v*)&winF[16 + c][4 * g];
        const half4v wvv = *(const half4v*)&winF[32 + c][4 * g];
        const float4v bq4 = *(const float4v*)&binS[4 * g];
        const float4v bk4 = *(const float4v*)&binS[16 + 4 * g];
        const float4v bv4 = *(const float4v*)&binS[32 + 4 * g];
        #pragma unroll
        for (int ti = 0; ti < 3; ++ti) {
            const int row = (wv * 3 + ti) * 16 + c;
            half4v hv = *(const half4v*)&hF[row][4 * g];
            hfr[ti] = hv;
            float4v dq = __builtin_amdgcn_mfma_f32_16x16x16f16(wq,  hv, zero4, 0, 0, 0);
            float4v dk = __builtin_amdgcn_mfma_f32_16x16x16f16(wk,  hv, zero4, 0, 0, 0);
            float4v dv = __builtin_amdgcn_mfma_f32_16x16x16f16(wvv, hv, zero4, 0, 0, 0);
            half4v kh;
            #pragma unroll
            for (int j = 0; j < 4; ++j) {
                qf[ti][j] = (_Float16)(dq[j] + bq4[j]);
                kh[j]     = (_Float16)(dk[j] + bk4[j]);
                vT[4 * g + j][row] = (_Float16)(dv[j] + bv4[j]);
            }
            *(half4v*)&kF[row][4 * g] = kh;
        }
    }
    __syncthreads();

    // ---- phase 3: full-row softmax attention, 3 q-tiles per wave ----
    // K/V fragments loaded once, reused by all 3 q-tiles.
    half4v kfA[9], vfA[9];
    #pragma unroll
    for (int kt = 0; kt < 9; ++kt) {
        kfA[kt] = *(const half4v*)&kF[kt * 16 + c][4 * g];
        vfA[kt] = *(const half4v*)&vT[c][kt * 16 + 4 * g];
    }

    float accm[4] = {0.f, 0.f, 0.f, 0.f};
    const float b1v = b1S;
    const float4v bo4   = *(const float4v*)&boutS[4 * g];
    const float4v ln1g4 = *(const float4v*)&ln1gS[4 * g];
    const float4v ln1b4 = *(const float4v*)&ln1bS[4 * g];
    const float4v ln2g4 = *(const float4v*)&ln2gS[4 * g];
    const float4v ln2b4 = *(const float4v*)&ln2bS[4 * g];
    const float4v w14   = *(const float4v*)&w1S[4 * g];
    const float4v w24   = *(const float4v*)&w2S[4 * g];
    const float4v b24   = *(const float4v*)&b2S[4 * g];
    const half4v wo = *(const half4v*)&woutF[c][4 * g];

    #pragma unroll
    for (int ti = 0; ti < 3; ++ti) {
        const int tile = wv * 3 + ti;
        // --- scores: 9 independent QK^T MFMAs ---
        float4v s[9];
        #pragma unroll
        for (int kt = 0; kt < 9; ++kt)
            s[kt] = __builtin_amdgcn_mfma_f32_16x16x16f16(kfA[kt], qf[ti], zero4, 0, 0, 0);
        // mask k-rows 130..143 (kt==8: valid only g==0, j<2)
        s[8][2] = -1e30f; s[8][3] = -1e30f;
        if (g > 0) { s[8][0] = -1e30f; s[8][1] = -1e30f; }
        // --- row max ---
        float m = fmaxf(fmaxf(s[0][0], s[0][1]), fmaxf(s[0][2], s[0][3]));
        #pragma unroll
        for (int kt = 1; kt < 9; ++kt)
            m = fmaxf(m, fmaxf(fmaxf(s[kt][0], s[kt][1]), fmaxf(s[kt][2], s[kt][3])));
        m = fmaxf(m, __shfl_xor(m, 16));
        m = fmaxf(m, __shfl_xor(m, 32));
        // --- exp, sum, pack ---
        half4v pf[9];
        float l = 0.f;
        #pragma unroll
        for (int kt = 0; kt < 9; ++kt) {
            float p0 = __expf(s[kt][0] - m), p1 = __expf(s[kt][1] - m);
            float p2 = __expf(s[kt][2] - m), p3 = __expf(s[kt][3] - m);
            l += (p0 + p1) + (p2 + p3);
            pf[kt] = {(_Float16)p0, (_Float16)p1, (_Float16)p2, (_Float16)p3};
        }
        l += __shfl_xor(l, 16);
        l += __shfl_xor(l, 32);
        // --- PV: two alternating accumulators to halve the MFMA dep-chain ---
        float4v Oa = zero4, Ob = zero4;
        #pragma unroll
        for (int kt = 0; kt < 9; kt += 2)
            Oa = __builtin_amdgcn_mfma_f32_16x16x16f16(vfA[kt], pf[kt], Oa, 0, 0, 0);
        #pragma unroll
        for (int kt = 1; kt < 9; kt += 2)
            Ob = __builtin_amdgcn_mfma_f32_16x16x16f16(vfA[kt], pf[kt], Ob, 0, 0, 0);
        const float inv = 1.0f / l;
        half4v cf;
        #pragma unroll
        for (int j = 0; j < 4; ++j) cf[j] = (_Float16)((Oa[j] + Ob[j]) * inv);
        // --- attn_out via MFMA, residual, LN1, FF, LN2, mean-accumulate ---
        float4v AO = __builtin_amdgcn_mfma_f32_16x16x16f16(wo, cf, zero4, 0, 0, 0);
        float h2[4], h3[4];
        #pragma unroll
        for (int j = 0; j < 4; ++j) h2[j] = (float)hfr[ti][j] + AO[j] + bo4[j];
        float s1 = (h2[0] + h2[1]) + (h2[2] + h2[3]);
        s1 += __shfl_xor(s1, 16); s1 += __shfl_xor(s1, 32);
        float mean = s1 * 0.0625f;
        float vv = 0.f;
        #pragma unroll
        for (int j = 0; j < 4; ++j) { float d = h2[j] - mean; vv += d * d; }
        vv += __shfl_xor(vv, 16); vv += __shfl_xor(vv, 32);
        float rstd = rsqrtf(vv * 0.0625f + 1e-5f);
        #pragma unroll
        for (int j = 0; j < 4; ++j)
            h2[j] = (h2[j] - mean) * rstd * ln1g4[j] + ln1b4[j];
        float fa = h2[0] * w14[0] + h2[1] * w14[1] + h2[2] * w14[2] + h2[3] * w14[3];
        fa += __shfl_xor(fa, 16); fa += __shfl_xor(fa, 32);
        float ffa = fmaxf(fa + b1v, 0.f);
        #pragma unroll
        for (int j = 0; j < 4; ++j) h3[j] = h2[j] + ffa * w24[j] + b24[j];
        float s2 = (h3[0] + h3[1]) + (h3[2] + h3[3]);
        s2 += __shfl_xor(s2, 16); s2 += __shfl_xor(s2, 32);
        float mean2 = s2 * 0.0625f;
        float v2 = 0.f;
        #pragma unroll
        for (int j = 0; j < 4; ++j) { float d = h3[j] - mean2; v2 += d * d; }
        v2 += __shfl_xor(v2, 16); v2 += __shfl_xor(v2, 32);
        float rstd2 = rsqrtf(v2 * 0.0625f + 1e-5f);
        if (tile * 16 + c < SEQ) {
            #pragma unroll
            for (int j = 0; j < 4; ++j)
                accm[j] += (h3[j] - mean2) * rstd2 * ln2g4[j] + ln2b4[j];
        }
    }

    // ---- mean over rows: reduce across the 16 c-lanes, then 3 waves ----
    #pragma unroll
    for (int off = 1; off < 16; off <<= 1) {
        #pragma unroll
        for (int j = 0; j < 4; ++j) accm[j] += __shfl_xor(accm[j], off);
    }
    if (c == 0) {
        #pragma unroll
        for (int j = 0; j < 4; ++j) psum[wv][4 * g + j] = accm[j];
    }
    __syncthreads();
    if (tid < 16) {
        float s = psum[0][tid] + psum[1][tid] + psum[2][tid];
        out[(size_t)b * 16 + tid] = s * (1.0f / 130.0f);
    }
}

extern "C" void kernel_launch(void* const* d_in, const int* in_sizes, int n_in,
                              void* d_out, int out_size, void* d_ws, size_t ws_size,
                              hipStream_t stream) {
    const float* x      = (const float*)d_in[0];
    const float* w_proj = (const float*)d_in[1];
    const float* b_proj = (const float*)d_in[2];
    const float* w_in   = (const float*)d_in[3];
    const float* b_in   = (const float*)d_in[4];
    const float* w_out  = (const float*)d_in[5];
    const float* b_out  = (const float*)d_in[6];
    const float* ln1_g  = (const float*)d_in[7];
    const float* ln1_b  = (const float*)d_in[8];
    const float* w1     = (const float*)d_in[9];
    const float* b1     = (const float*)d_in[10];
    const float* w2     = (const float*)d_in[11];
    const float* b2     = (const float*)d_in[12];
    const float* ln2_g  = (const float*)d_in[13];
    const float* ln2_b  = (const float*)d_in[14];

    float2* pe = (float2*)d_ws;
    pe_kernel<<<(SEQ * 8 + 255) / 256, 256, 0, stream>>>(b_proj, pe);

    int B = in_sizes[0] / LIN;
    st_kernel<<<B, 192, 0, stream>>>(x, w_proj, w_in, b_in,
                                     w_out, b_out, ln1_g, ln1_b,
                                     w1, b1, w2, b2, ln2_g, ln2_b,
                                     pe, (float*)d_out);
}

// Round 10
// 143.189 us; speedup vs baseline: 1.0074x; 1.0074x over previous
//
#include <hip/hip_runtime.h>
#include <math.h>

#define SEQ 130
#define SPAD 144      // 9 tiles of 16
#define EMB 16
#define LIN 1039
#define LPAD 1040
#define FP 20         // f16 row pad (halves) for hF/kF/winF/woutF
#define VTP 152       // vT row pad (halves)
#define NB 8          // batches per block

typedef __attribute__((ext_vector_type(4))) _Float16 half4v;
typedef __attribute__((ext_vector_type(4))) float float4v;

// ---- posenc (+ b_proj folded) table: computed once per launch into d_ws ----
__global__ void pe_kernel(const float* __restrict__ b_proj, float2* __restrict__ pe) {
    int idx = blockIdx.x * 256 + threadIdx.x;
    if (idx < SEQ * 8) {
        int s = idx >> 3, i = idx & 7;
        float div = expf(-(float)(2 * i) * 0.57564627324851149f); // ln(1e4)/16
        float ang = (float)s * div;
        pe[idx] = make_float2(sinf(ang) + b_proj[2 * i],
                              cosf(ang) + b_proj[2 * i + 1]);
    }
}

// 256 threads = 4 waves; wave wv owns q-tiles {wv, wv+4, 8 (wv==0 only)}.
// Each block processes NB batches serially; whole grid co-resident.
__global__ __launch_bounds__(256, 4) void st_kernel(
    const float* __restrict__ x,
    const float* __restrict__ w_proj,
    const float* __restrict__ w_in,  const float* __restrict__ b_in,
    const float* __restrict__ w_out, const float* __restrict__ b_out,
    const float* __restrict__ ln1_g, const float* __restrict__ ln1_b,
    const float* __restrict__ w1,    const float* __restrict__ b1,
    const float* __restrict__ w2,    const float* __restrict__ b2,
    const float* __restrict__ ln2_g, const float* __restrict__ ln2_b,
    const float2* __restrict__ pe,
    int nbat,
    float* __restrict__ out)
{
    __shared__ __align__(16) float xs[LPAD];
    __shared__ __align__(8) _Float16 hF[SPAD][FP];
    __shared__ __align__(8) _Float16 kF[SPAD][FP];
    __shared__ __align__(16) _Float16 vT[EMB][VTP];   // V transposed: vT[e][k]
    __shared__ __align__(8) _Float16 winF[48][FP];
    __shared__ __align__(8) _Float16 woutF[16][FP];
    __shared__ float wprojS[EMB][9];
    __shared__ __align__(16) float binS[48];
    __shared__ __align__(16) float boutS[16], w1S[16], w2S[16], b2S[16];
    __shared__ __align__(16) float ln1gS[16], ln1bS[16], ln2gS[16], ln2bS[16];
    __shared__ float b1S;
    __shared__ float psum[4][16];

    const int tid = threadIdx.x;

    // ---- stage parameters (once per block) ----
    if (tid < 128) wprojS[tid >> 3][tid & 7] = w_proj[tid];
    for (int i = tid; i < 384; i += 256) {          // w_in -> f16 (q rows ×0.25)
        int f = i >> 3, ep = i & 7;
        float sc = (f < 16) ? 0.25f : 1.0f;
        union { _Float16 h[2]; unsigned u; } pk;
        pk.h[0] = (_Float16)(w_in[f * 16 + 2 * ep] * sc);
        pk.h[1] = (_Float16)(w_in[f * 16 + 2 * ep + 1] * sc);
        *(unsigned*)&winF[f][2 * ep] = pk.u;
    }
    if (tid < 128) {                                 // w_out -> f16
        int f = tid >> 3, ep = tid & 7;
        union { _Float16 h[2]; unsigned u; } pk;
        pk.h[0] = (_Float16)w_out[f * 16 + 2 * ep];
        pk.h[1] = (_Float16)w_out[f * 16 + 2 * ep + 1];
        *(unsigned*)&woutF[f][2 * ep] = pk.u;
    }
    if (tid < 48) binS[tid] = b_in[tid] * ((tid < 16) ? 0.25f : 1.0f);
    if (tid >= 64 && tid < 80) {
        int e = tid - 64;
        boutS[e] = b_out[e]; w1S[e] = w1[e]; w2S[e] = w2[e]; b2S[e] = b2[e];
    }
    if (tid >= 80 && tid < 96) {
        int e = tid - 80;
        ln1gS[e] = ln1_g[e]; ln1bS[e] = ln1_b[e];
        ln2gS[e] = ln2_g[e]; ln2bS[e] = ln2_b[e];
    }
    if (tid == 96) b1S = b1[0];
    if (tid < 140) {                                 // zero hF pad rows 130..143
        int r = SEQ + tid / 10, w = tid % 10;
        *(unsigned*)&hF[r][2 * w] = 0u;
    }

    // ---- lane geometry ----
    const int lane = tid & 63;
    const int wv   = tid >> 6;          // 0..3
    const int c    = lane & 15;
    const int g    = lane >> 4;
    const float4v zero4 = {0.f, 0.f, 0.f, 0.f};

    // ---- prefetch batch 0's x row into regs ----
    float xr[5];
    {
        const int batch0 = blockIdx.x * NB;
        const float* xrow = x + (size_t)batch0 * LIN;
        #pragma unroll
        for (int u = 0; u < 5; ++u) {
            int i = tid + u * 256;
            xr[u] = (i < LIN && batch0 < nbat) ? xrow[i] : 0.0f;
        }
    }
    __syncthreads();   // weights + hF pad ready

    for (int bi = 0; bi < NB; ++bi) {
        const int batch = blockIdx.x * NB + bi;
        if (batch >= nbat) break;

        // ---- write xs from prefetched regs ----
        #pragma unroll
        for (int u = 0; u < 5; ++u) {
            int i = tid + u * 256;
            if (i < LPAD) xs[i] = xr[u];
        }
        __syncthreads();   // bar A: xs ready

        // ---- prefetch next batch's x (lands during p1..p3) ----
        if (bi + 1 < NB && batch + 1 < nbat) {
            const float* xrow = x + (size_t)(batch + 1) * LIN;
            #pragma unroll
            for (int u = 0; u < 5; ++u) {
                int i = tid + u * 256;
                xr[u] = (i < LIN) ? xrow[i] : 0.0f;
            }
        }

        // ---- phase 1: h = patches @ w_proj^T + (posenc+b_proj) -> f16 ----
        for (int idx = tid; idx < SEQ * 8; idx += 256) {
            int s = idx >> 3, i = idx & 7;
            const float* xp = &xs[s * 8];
            float a0 = 0.f, a1 = 0.f;
            #pragma unroll
            for (int p = 0; p < 8; ++p) {
                float xv = xp[p];
                a0 += xv * wprojS[2 * i][p];
                a1 += xv * wprojS[2 * i + 1][p];
            }
            float2 pp = pe[idx];
            a0 += pp.x; a1 += pp.y;
            union { _Float16 h[2]; unsigned u; } pk;
            pk.h[0] = (_Float16)a0; pk.h[1] = (_Float16)a1;
            *(unsigned*)&hF[s][2 * i] = pk.u;
        }
        __syncthreads();   // bar B: hF ready

        // ---- phase 2: qkv via MFMA; q in regs, k -> kF, v -> vT ----
        half4v qf0, qf1, qf2, hf0, hf1, hf2;
        {
            const half4v wq  = *(const half4v*)&winF[c][4 * g];
            const half4v wk  = *(const half4v*)&winF[16 + c][4 * g];
            const half4v wvv = *(const half4v*)&winF[32 + c][4 * g];
            const float4v bq4 = *(const float4v*)&binS[4 * g];
            const float4v bk4 = *(const float4v*)&binS[16 + 4 * g];
            const float4v bv4 = *(const float4v*)&binS[32 + 4 * g];

#define QKV_TILE(T, ST) do {                                                   \
            const int row = (ST) * 16 + c;                                     \
            hf##T = *(const half4v*)&hF[row][4 * g];                           \
            float4v dq = __builtin_amdgcn_mfma_f32_16x16x16f16(wq,  hf##T, zero4, 0, 0, 0); \
            float4v dk = __builtin_amdgcn_mfma_f32_16x16x16f16(wk,  hf##T, zero4, 0, 0, 0); \
            float4v dv = __builtin_amdgcn_mfma_f32_16x16x16f16(wvv, hf##T, zero4, 0, 0, 0); \
            half4v kh;                                                         \
            _Pragma("unroll") for (int j = 0; j < 4; ++j) {                    \
                qf##T[j] = (_Float16)(dq[j] + bq4[j]);                         \
                kh[j]    = (_Float16)(dk[j] + bk4[j]);                         \
                vT[4 * g + j][row] = (_Float16)(dv[j] + bv4[j]);               \
            }                                                                  \
            *(half4v*)&kF[row][4 * g] = kh;                                    \
        } while (0)

            QKV_TILE(0, wv);
            QKV_TILE(1, wv + 4);
            if (wv == 0) { QKV_TILE(2, 8); } else { qf2 = qf0; hf2 = hf0; }
#undef QKV_TILE
        }
        __syncthreads();   // bar C: kF/vT ready

        // ---- phase 3: full-row softmax attention + fused epilogue ----
        half4v kfA[9], vfA[9];
        #pragma unroll
        for (int kt = 0; kt < 9; ++kt) {
            kfA[kt] = *(const half4v*)&kF[kt * 16 + c][4 * g];
            vfA[kt] = *(const half4v*)&vT[c][kt * 16 + 4 * g];
        }
        float accm[4] = {0.f, 0.f, 0.f, 0.f};
        const half4v wo = *(const half4v*)&woutF[c][4 * g];
        const float b1v = b1S;

#define DO_TILE(T, ST, ON) do { if (ON) {                                      \
        float4v s[9];                                                          \
        _Pragma("unroll") for (int kt = 0; kt < 9; ++kt)                       \
            s[kt] = __builtin_amdgcn_mfma_f32_16x16x16f16(kfA[kt], qf##T, zero4, 0, 0, 0); \
        s[8][2] = -1e30f; s[8][3] = -1e30f;                                    \
        if (g > 0) { s[8][0] = -1e30f; s[8][1] = -1e30f; }                     \
        float m = fmaxf(fmaxf(s[0][0], s[0][1]), fmaxf(s[0][2], s[0][3]));     \
        _Pragma("unroll") for (int kt = 1; kt < 9; ++kt)                       \
            m = fmaxf(m, fmaxf(fmaxf(s[kt][0], s[kt][1]), fmaxf(s[kt][2], s[kt][3]))); \
        m = fmaxf(m, __shfl_xor(m, 16));                                       \
        m = fmaxf(m, __shfl_xor(m, 32));                                       \
        half4v pf[9];                                                          \
        float l = 0.f;                                                         \
        _Pragma("unroll") for (int kt = 0; kt < 9; ++kt) {                     \
            float p0 = __expf(s[kt][0] - m), p1 = __expf(s[kt][1] - m);        \
            float p2 = __expf(s[kt][2] - m), p3 = __expf(s[kt][3] - m);        \
            l += (p0 + p1) + (p2 + p3);                                        \
            pf[kt] = {(_Float16)p0, (_Float16)p1, (_Float16)p2, (_Float16)p3}; \
        }                                                                      \
        l += __shfl_xor(l, 16);                                                \
        l += __shfl_xor(l, 32);                                                \
        float4v Oa = zero4, Ob = zero4;                                        \
        _Pragma("unroll") for (int kt = 0; kt < 9; kt += 2)                    \
            Oa = __builtin_amdgcn_mfma_f32_16x16x16f16(vfA[kt], pf[kt], Oa, 0, 0, 0); \
        _Pragma("unroll") for (int kt = 1; kt < 9; kt += 2)                    \
            Ob = __builtin_amdgcn_mfma_f32_16x16x16f16(vfA[kt], pf[kt], Ob, 0, 0, 0); \
        const float inv = 1.0f / l;                                            \
        half4v cf;                                                             \
        _Pragma("unroll") for (int j = 0; j < 4; ++j)                          \
            cf[j] = (_Float16)((Oa[j] + Ob[j]) * inv);                         \
        float4v AO = __builtin_amdgcn_mfma_f32_16x16x16f16(wo, cf, zero4, 0, 0, 0); \
        const float4v bo4   = *(const float4v*)&boutS[4 * g];                  \
        const float4v ln1g4 = *(const float4v*)&ln1gS[4 * g];                  \
        const float4v ln1b4 = *(const float4v*)&ln1bS[4 * g];                  \
        const float4v ln2g4 = *(const float4v*)&ln2gS[4 * g];                  \
        const float4v ln2b4 = *(const float4v*)&ln2bS[4 * g];                  \
        const float4v w14   = *(const float4v*)&w1S[4 * g];                    \
        const float4v w24   = *(const float4v*)&w2S[4 * g];                    \
        const float4v b24   = *(const float4v*)&b2S[4 * g];                    \
        float h2[4], h3[4];                                                    \
        _Pragma("unroll") for (int j = 0; j < 4; ++j)                          \
            h2[j] = (float)hf##T[j] + AO[j] + bo4[j];                          \
        float s1 = (h2[0] + h2[1]) + (h2[2] + h2[3]);                          \
        s1 += __shfl_xor(s1, 16); s1 += __shfl_xor(s1, 32);                    \
        float mean = s1 * 0.0625f;                                             \
        float vv = 0.f;                                                        \
        _Pragma("unroll") for (int j = 0; j < 4; ++j) {                        \
            float d = h2[j] - mean; vv += d * d; }                             \
        vv += __shfl_xor(vv, 16); vv += __shfl_xor(vv, 32);                    \
        float rstd = rsqrtf(vv * 0.0625f + 1e-5f);                             \
        _Pragma("unroll") for (int j = 0; j < 4; ++j)                          \
            h2[j] = (h2[j] - mean) * rstd * ln1g4[j] + ln1b4[j];               \
        float fa = h2[0]*w14[0] + h2[1]*w14[1] + h2[2]*w14[2] + h2[3]*w14[3];  \
        fa += __shfl_xor(fa, 16); fa += __shfl_xor(fa, 32);                    \
        float ffa = fmaxf(fa + b1v, 0.f);                                      \
        _Pragma("unroll") for (int j = 0; j < 4; ++j)                          \
            h3[j] = h2[j] + ffa * w24[j] + b24[j];                             \
        float s2 = (h3[0] + h3[1]) + (h3[2] + h3[3]);                          \
        s2 += __shfl_xor(s2, 16); s2 += __shfl_xor(s2, 32);                    \
        float mean2 = s2 * 0.0625f;                                            \
        float v2 = 0.f;                                                        \
        _Pragma("unroll") for (int j = 0; j < 4; ++j) {                        \
            float d = h3[j] - mean2; v2 += d * d; }                            \
        v2 += __shfl_xor(v2, 16); v2 += __shfl_xor(v2, 32);                    \
        float rstd2 = rsqrtf(v2 * 0.0625f + 1e-5f);                            \
        if ((ST) * 16 + c < SEQ) {                                             \
            _Pragma("unroll") for (int j = 0; j < 4; ++j)                      \
                accm[j] += (h3[j] - mean2) * rstd2 * ln2g4[j] + ln2b4[j];      \
        } } } while (0)

        DO_TILE(0, wv, true);
        DO_TILE(1, wv + 4, true);
        DO_TILE(2, 8, (wv == 0));
#undef DO_TILE

        // ---- mean over rows: reduce across 16 c-lanes, stash per wave ----
        #pragma unroll
        for (int off = 1; off < 16; off <<= 1) {
            #pragma unroll
            for (int j = 0; j < 4; ++j) accm[j] += __shfl_xor(accm[j], off);
        }
        if (c == 0) {
            #pragma unroll
            for (int j = 0; j < 4; ++j) psum[wv][4 * g + j] = accm[j];
        }
        __syncthreads();   // bar D: psum ready; kF/vT reads done
        if (tid < 16) {
            float s = psum[0][tid] + psum[1][tid] + psum[2][tid] + psum[3][tid];
            out[(size_t)batch * 16 + tid] = s * (1.0f / 130.0f);
        }
        // next iteration's xs write is safe: xs readers finished before bar B
    }
}

extern "C" void kernel_launch(void* const* d_in, const int* in_sizes, int n_in,
                              void* d_out, int out_size, void* d_ws, size_t ws_size,
                              hipStream_t stream) {
    const float* x      = (const float*)d_in[0];
    const float* w_proj = (const float*)d_in[1];
    const float* b_proj = (const float*)d_in[2];
    const float* w_in   = (const float*)d_in[3];
    const float* b_in   = (const float*)d_in[4];
    const float* w_out  = (const float*)d_in[5];
    const float* b_out  = (const float*)d_in[6];
    const float* ln1_g  = (const float*)d_in[7];
    const float* ln1_b  = (const float*)d_in[8];
    const float* w1     = (const float*)d_in[9];
    const float* b1     = (const float*)d_in[10];
    const float* w2     = (const float*)d_in[11];
    const float* b2     = (const float*)d_in[12];
    const float* ln2_g  = (const float*)d_in[13];
    const float* ln2_b  = (const float*)d_in[14];

    float2* pe = (float2*)d_ws;
    pe_kernel<<<(SEQ * 8 + 255) / 256, 256, 0, stream>>>(b_proj, pe);

    int B = in_sizes[0] / LIN;
    int grid = (B + NB - 1) / NB;
    st_kernel<<<grid, 256, 0, stream>>>(x, w_proj, w_in, b_in,
                                        w_out, b_out, ln1_g, ln1_b,
                                        w1, b1, w2, b2, ln2_g, ln2_b,
                                        pe, B, (float*)d_out);
}

// Round 11
// 119.170 us; speedup vs baseline: 1.2105x; 1.2016x over previous
//
#include <hip/hip_runtime.h>
#include <math.h>

#define SEQ 130
#define SPAD 144      // 9 tiles of 16
#define EMB 16
#define LIN 1039
#define LPAD 1040
#define FP 20         // f16 row pad (halves) for hF/kF/winF/woutF
#define VTP 152       // vT row pad (halves)
#define NB 8          // batches per block

typedef __attribute__((ext_vector_type(4))) _Float16 half4v;
typedef __attribute__((ext_vector_type(4))) float float4v;

// ---- posenc (+ b_proj folded) table: computed once per launch into d_ws ----
__global__ void pe_kernel(const float* __restrict__ b_proj, float2* __restrict__ pe) {
    int idx = blockIdx.x * 256 + threadIdx.x;
    if (idx < SEQ * 8) {
        int s = idx >> 3, i = idx & 7;
        float div = expf(-(float)(2 * i) * 0.57564627324851149f); // ln(1e4)/16
        float ang = (float)s * div;
        pe[idx] = make_float2(sinf(ang) + b_proj[2 * i],
                              cosf(ang) + b_proj[2 * i + 1]);
    }
}

// 256 threads = 4 waves; wave wv owns q-tiles {wv, wv+4, 8 (wv==0 only)}.
// Each block processes NB batches serially; whole grid co-resident.
__global__ __launch_bounds__(256) void st_kernel(
    const float* __restrict__ x,
    const float* __restrict__ w_proj,
    const float* __restrict__ w_in,  const float* __restrict__ b_in,
    const float* __restrict__ w_out, const float* __restrict__ b_out,
    const float* __restrict__ ln1_g, const float* __restrict__ ln1_b,
    const float* __restrict__ w1,    const float* __restrict__ b1,
    const float* __restrict__ w2,    const float* __restrict__ b2,
    const float* __restrict__ ln2_g, const float* __restrict__ ln2_b,
    const float2* __restrict__ pe,
    int nbat,
    float* __restrict__ out)
{
    __shared__ __align__(16) float xs[LPAD];
    __shared__ __align__(8) _Float16 hF[SPAD][FP];
    __shared__ __align__(8) _Float16 kF[SPAD][FP];
    __shared__ __align__(16) _Float16 vT[EMB][VTP];   // V transposed: vT[e][k]
    __shared__ __align__(8) _Float16 winF[48][FP];
    __shared__ __align__(8) _Float16 woutF[16][FP];
    __shared__ float wprojS[EMB][9];
    __shared__ __align__(16) float binS[48];
    __shared__ __align__(16) float boutS[16], w1S[16], w2S[16], b2S[16];
    __shared__ __align__(16) float ln1gS[16], ln1bS[16], ln2gS[16], ln2bS[16];
    __shared__ float b1S;
    __shared__ float psum[4][16];

    const int tid = threadIdx.x;

    // ---- stage parameters (once per block) ----
    if (tid < 128) wprojS[tid >> 3][tid & 7] = w_proj[tid];
    for (int i = tid; i < 384; i += 256) {          // w_in -> f16 (q rows ×0.25)
        int f = i >> 3, ep = i & 7;
        float sc = (f < 16) ? 0.25f : 1.0f;
        union { _Float16 h[2]; unsigned u; } pk;
        pk.h[0] = (_Float16)(w_in[f * 16 + 2 * ep] * sc);
        pk.h[1] = (_Float16)(w_in[f * 16 + 2 * ep + 1] * sc);
        *(unsigned*)&winF[f][2 * ep] = pk.u;
    }
    if (tid < 128) {                                 // w_out -> f16
        int f = tid >> 3, ep = tid & 7;
        union { _Float16 h[2]; unsigned u; } pk;
        pk.h[0] = (_Float16)w_out[f * 16 + 2 * ep];
        pk.h[1] = (_Float16)w_out[f * 16 + 2 * ep + 1];
        *(unsigned*)&woutF[f][2 * ep] = pk.u;
    }
    if (tid < 48) binS[tid] = b_in[tid] * ((tid < 16) ? 0.25f : 1.0f);
    if (tid >= 64 && tid < 80) {
        int e = tid - 64;
        boutS[e] = b_out[e]; w1S[e] = w1[e]; w2S[e] = w2[e]; b2S[e] = b2[e];
    }
    if (tid >= 80 && tid < 96) {
        int e = tid - 80;
        ln1gS[e] = ln1_g[e]; ln1bS[e] = ln1_b[e];
        ln2gS[e] = ln2_g[e]; ln2bS[e] = ln2_b[e];
    }
    if (tid == 96) b1S = b1[0];
    if (tid < 140) {                                 // zero hF pad rows 130..143
        int r = SEQ + tid / 10, w = tid % 10;
        *(unsigned*)&hF[r][2 * w] = 0u;
    }

    // ---- lane geometry ----
    const int lane = tid & 63;
    const int wv   = tid >> 6;          // 0..3
    const int c    = lane & 15;
    const int g    = lane >> 4;
    const float4v zero4 = {0.f, 0.f, 0.f, 0.f};

    // ---- prefetch batch 0's x row into regs ----
    float xr[5];
    {
        const int batch0 = blockIdx.x * NB;
        const float* xrow = x + (size_t)batch0 * LIN;
        #pragma unroll
        for (int u = 0; u < 5; ++u) {
            int i = tid + u * 256;
            xr[u] = (i < LIN && batch0 < nbat) ? xrow[i] : 0.0f;
        }
    }
    __syncthreads();   // weights + hF pad ready

    for (int bi = 0; bi < NB; ++bi) {
        const int batch = blockIdx.x * NB + bi;
        if (batch >= nbat) break;

        // ---- write xs from prefetched regs ----
        #pragma unroll
        for (int u = 0; u < 5; ++u) {
            int i = tid + u * 256;
            if (i < LPAD) xs[i] = xr[u];
        }
        __syncthreads();   // bar A: xs ready

        // ---- prefetch next batch's x (lands during p1..p3) ----
        if (bi + 1 < NB && batch + 1 < nbat) {
            const float* xrow = x + (size_t)(batch + 1) * LIN;
            #pragma unroll
            for (int u = 0; u < 5; ++u) {
                int i = tid + u * 256;
                xr[u] = (i < LIN) ? xrow[i] : 0.0f;
            }
        }

        // ---- phase 1: h = patches @ w_proj^T + (posenc+b_proj) -> f16 ----
        for (int idx = tid; idx < SEQ * 8; idx += 256) {
            int s = idx >> 3, i = idx & 7;
            const float* xp = &xs[s * 8];
            float a0 = 0.f, a1 = 0.f;
            #pragma unroll
            for (int p = 0; p < 8; ++p) {
                float xv = xp[p];
                a0 += xv * wprojS[2 * i][p];
                a1 += xv * wprojS[2 * i + 1][p];
            }
            float2 pp = pe[idx];
            a0 += pp.x; a1 += pp.y;
            union { _Float16 h[2]; unsigned u; } pk;
            pk.h[0] = (_Float16)a0; pk.h[1] = (_Float16)a1;
            *(unsigned*)&hF[s][2 * i] = pk.u;
        }
        __syncthreads();   // bar B: hF ready

        // ---- phase 2: qkv via MFMA; q in regs, k -> kF, v -> vT ----
        half4v qf0, qf1, qf2, hf0, hf1, hf2;
        {
            const half4v wq  = *(const half4v*)&winF[c][4 * g];
            const half4v wk  = *(const half4v*)&winF[16 + c][4 * g];
            const half4v wvv = *(const half4v*)&winF[32 + c][4 * g];
            const float4v bq4 = *(const float4v*)&binS[4 * g];
            const float4v bk4 = *(const float4v*)&binS[16 + 4 * g];
            const float4v bv4 = *(const float4v*)&binS[32 + 4 * g];

#define QKV_TILE(T, ST) do {                                                   \
            const int row = (ST) * 16 + c;                                     \
            hf##T = *(const half4v*)&hF[row][4 * g];                           \
            float4v dq = __builtin_amdgcn_mfma_f32_16x16x16f16(wq,  hf##T, zero4, 0, 0, 0); \
            float4v dk = __builtin_amdgcn_mfma_f32_16x16x16f16(wk,  hf##T, zero4, 0, 0, 0); \
            float4v dv = __builtin_amdgcn_mfma_f32_16x16x16f16(wvv, hf##T, zero4, 0, 0, 0); \
            half4v kh;                                                         \
            _Pragma("unroll") for (int j = 0; j < 4; ++j) {                    \
                qf##T[j] = (_Float16)(dq[j] + bq4[j]);                         \
                kh[j]    = (_Float16)(dk[j] + bk4[j]);                         \
                vT[4 * g + j][row] = (_Float16)(dv[j] + bv4[j]);               \
            }                                                                  \
            *(half4v*)&kF[row][4 * g] = kh;                                    \
        } while (0)

            QKV_TILE(0, wv);
            QKV_TILE(1, wv + 4);
            if (wv == 0) { QKV_TILE(2, 8); } else { qf2 = qf0; hf2 = hf0; }
#undef QKV_TILE
        }
        __syncthreads();   // bar C: kF/vT ready

        // ---- phase 3: full-row softmax attention + fused epilogue ----
        half4v kfA[9], vfA[9];
        #pragma unroll
        for (int kt = 0; kt < 9; ++kt) {
            kfA[kt] = *(const half4v*)&kF[kt * 16 + c][4 * g];
            vfA[kt] = *(const half4v*)&vT[c][kt * 16 + 4 * g];
        }
        float accm[4] = {0.f, 0.f, 0.f, 0.f};
        const half4v wo = *(const half4v*)&woutF[c][4 * g];
        const float b1v = b1S;

#define DO_TILE(T, ST, ON) do { if (ON) {                                      \
        float4v s[9];                                                          \
        _Pragma("unroll") for (int kt = 0; kt < 9; ++kt)                       \
            s[kt] = __builtin_amdgcn_mfma_f32_16x16x16f16(kfA[kt], qf##T, zero4, 0, 0, 0); \
        s[8][2] = -1e30f; s[8][3] = -1e30f;                                    \
        if (g > 0) { s[8][0] = -1e30f; s[8][1] = -1e30f; }                     \
        float m = fmaxf(fmaxf(s[0][0], s[0][1]), fmaxf(s[0][2], s[0][3]));     \
        _Pragma("unroll") for (int kt = 1; kt < 9; ++kt)                       \
            m = fmaxf(m, fmaxf(fmaxf(s[kt][0], s[kt][1]), fmaxf(s[kt][2], s[kt][3]))); \
        m = fmaxf(m, __shfl_xor(m, 16));                                       \
        m = fmaxf(m, __shfl_xor(m, 32));                                       \
        half4v pf[9];                                                          \
        float l = 0.f;                                                         \
        _Pragma("unroll") for (int kt = 0; kt < 9; ++kt) {                     \
            float p0 = __expf(s[kt][0] - m), p1 = __expf(s[kt][1] - m);        \
            float p2 = __expf(s[kt][2] - m), p3 = __expf(s[kt][3] - m);        \
            l += (p0 + p1) + (p2 + p3);                                        \
            pf[kt] = {(_Float16)p0, (_Float16)p1, (_Float16)p2, (_Float16)p3}; \
        }                                                                      \
        l += __shfl_xor(l, 16);                                                \
        l += __shfl_xor(l, 32);                                                \
        float4v Oa = zero4, Ob = zero4;                                        \
        _Pragma("unroll") for (int kt = 0; kt < 9; kt += 2)                    \
            Oa = __builtin_amdgcn_mfma_f32_16x16x16f16(vfA[kt], pf[kt], Oa, 0, 0, 0); \
        _Pragma("unroll") for (int kt = 1; kt < 9; kt += 2)                    \
            Ob = __builtin_amdgcn_mfma_f32_16x16x16f16(vfA[kt], pf[kt], Ob, 0, 0, 0); \
        const float inv = 1.0f / l;                                            \
        half4v cf;                                                             \
        _Pragma("unroll") for (int j = 0; j < 4; ++j)                          \
            cf[j] = (_Float16)((Oa[j] + Ob[j]) * inv);                         \
        float4v AO = __builtin_amdgcn_mfma_f32_16x16x16f16(wo, cf, zero4, 0, 0, 0); \
        const float4v bo4   = *(const float4v*)&boutS[4 * g];                  \
        const float4v ln1g4 = *(const float4v*)&ln1gS[4 * g];                  \
        const float4v ln1b4 = *(const float4v*)&ln1bS[4 * g];                  \
        const float4v ln2g4 = *(const float4v*)&ln2gS[4 * g];                  \
        const float4v ln2b4 = *(const float4v*)&ln2bS[4 * g];                  \
        const float4v w14   = *(const float4v*)&w1S[4 * g];                    \
        const float4v w24   = *(const float4v*)&w2S[4 * g];                    \
        const float4v b24   = *(const float4v*)&b2S[4 * g];                    \
        float h2[4], h3[4];                                                    \
        _Pragma("unroll") for (int j = 0; j < 4; ++j)                          \
            h2[j] = (float)hf##T[j] + AO[j] + bo4[j];                          \
        float s1 = (h2[0] + h2[1]) + (h2[2] + h2[3]);                          \
        s1 += __shfl_xor(s1, 16); s1 += __shfl_xor(s1, 32);                    \
        float mean = s1 * 0.0625f;                                             \
        float vv = 0.f;                                                        \
        _Pragma("unroll") for (int j = 0; j < 4; ++j) {                        \
            float d = h2[j] - mean; vv += d * d; }                             \
        vv += __shfl_xor(vv, 16); vv += __shfl_xor(vv, 32);                    \
        float rstd = rsqrtf(vv * 0.0625f + 1e-5f);                             \
        _Pragma("unroll") for (int j = 0; j < 4; ++j)                          \
            h2[j] = (h2[j] - mean) * rstd * ln1g4[j] + ln1b4[j];               \
        float fa = h2[0]*w14[0] + h2[1]*w14[1] + h2[2]*w14[2] + h2[3]*w14[3];  \
        fa += __shfl_xor(fa, 16); fa += __shfl_xor(fa, 32);                    \
        float ffa = fmaxf(fa + b1v, 0.f);                                      \
        _Pragma("unroll") for (int j = 0; j < 4; ++j)                          \
            h3[j] = h2[j] + ffa * w24[j] + b24[j];                             \
        float s2 = (h3[0] + h3[1]) + (h3[2] + h3[3]);                          \
        s2 += __shfl_xor(s2, 16); s2 += __shfl_xor(s2, 32);                    \
        float mean2 = s2 * 0.0625f;                                            \
        float v2 = 0.f;                                                        \
        _Pragma("unroll") for (int j = 0; j < 4; ++j) {                        \
            float d = h3[j] - mean2; v2 += d * d; }                            \
        v2 += __shfl_xor(v2, 16); v2 += __shfl_xor(v2, 32);                    \
        float rstd2 = rsqrtf(v2 * 0.0625f + 1e-5f);                            \
        if ((ST) * 16 + c < SEQ) {                                             \
            _Pragma("unroll") for (int j = 0; j < 4; ++j)                      \
                accm[j] += (h3[j] - mean2) * rstd2 * ln2g4[j] + ln2b4[j];      \
        } } } while (0)

        DO_TILE(0, wv, true);
        DO_TILE(1, wv + 4, true);
        DO_TILE(2, 8, (wv == 0));
#undef DO_TILE

        // ---- mean over rows: reduce across 16 c-lanes, stash per wave ----
        #pragma unroll
        for (int off = 1; off < 16; off <<= 1) {
            #pragma unroll
            for (int j = 0; j < 4; ++j) accm[j] += __shfl_xor(accm[j], off);
        }
        if (c == 0) {
            #pragma unroll
            for (int j = 0; j < 4; ++j) psum[wv][4 * g + j] = accm[j];
        }
        __syncthreads();   // bar D: psum ready; kF/vT reads done
        if (tid < 16) {
            float s = psum[0][tid] + psum[1][tid] + psum[2][tid] + psum[3][tid];
            out[(size_t)batch * 16 + tid] = s * (1.0f / 130.0f);
        }
        // next iteration's xs write is safe: xs readers finished before bar B
    }
}

extern "C" void kernel_launch(void* const* d_in, const int* in_sizes, int n_in,
                              void* d_out, int out_size, void* d_ws, size_t ws_size,
                              hipStream_t stream) {
    const float* x      = (const float*)d_in[0];
    const float* w_proj = (const float*)d_in[1];
    const float* b_proj = (const float*)d_in[2];
    const float* w_in   = (const float*)d_in[3];
    const float* b_in   = (const float*)d_in[4];
    const float* w_out  = (const float*)d_in[5];
    const float* b_out  = (const float*)d_in[6];
    const float* ln1_g  = (const float*)d_in[7];
    const float* ln1_b  = (const float*)d_in[8];
    const float* w1     = (const float*)d_in[9];
    const float* b1     = (const float*)d_in[10];
    const float* w2     = (const float*)d_in[11];
    const float* b2     = (const float*)d_in[12];
    const float* ln2_g  = (const float*)d_in[13];
    const float* ln2_b  = (const float*)d_in[14];

    float2* pe = (float2*)d_ws;
    pe_kernel<<<(SEQ * 8 + 255) / 256, 256, 0, stream>>>(b_proj, pe);

    int B = in_sizes[0] / LIN;
    int grid = (B + NB - 1) / NB;
    st_kernel<<<grid, 256, 0, stream>>>(x, w_proj, w_in, b_in,
                                        w_out, b_out, ln1_g, ln1_b,
                                        w1, b1, w2, b2, ln2_g, ln2_b,
                                        pe, B, (float*)d_out);
}

// Round 12
// 112.595 us; speedup vs baseline: 1.2812x; 1.0584x over previous
//
#include <hip/hip_runtime.h>
#include <math.h>

#define SEQ 130
#define EMB 16
#define LIN 1039
#define NB 4          // batches per wave
#define WPB 4         // waves per block (256 threads)

typedef __attribute__((ext_vector_type(4))) _Float16 half4v;
typedef __attribute__((ext_vector_type(4))) float float4v;

// pe2[s][e] = posenc(s,e) + b_proj[e] for s<SEQ; 0 for s in [SEQ,144)
__global__ void pe_kernel(const float* __restrict__ b_proj, float* __restrict__ pe2) {
    int idx = blockIdx.x * 256 + threadIdx.x;   // s*16+e
    if (idx < 144 * 16) {
        int s = idx >> 4, e = idx & 15;
        float v = 0.f;
        if (s < SEQ) {
            int i = e >> 1;
            float div = expf(-(float)(2 * i) * 0.57564627324851149f); // ln(1e4)/16
            float ang = (float)s * div;
            v = ((e & 1) ? cosf(ang) : sinf(ang)) + b_proj[e];
        }
        pe2[idx] = v;
    }
}

// One wave = one batch end-to-end. No LDS, no barriers.
// frag(c,g,j) = M[c][4g+j]; D = mfma(M1,M2) => D[c][f] = sum_k M1[f][k]*M2[c][k]
__global__ __launch_bounds__(256) void st_kernel(
    const float* __restrict__ x,
    const float* __restrict__ w_proj,
    const float* __restrict__ w_in,  const float* __restrict__ b_in,
    const float* __restrict__ w_out, const float* __restrict__ b_out,
    const float* __restrict__ ln1_g, const float* __restrict__ ln1_b,
    const float* __restrict__ w1,    const float* __restrict__ b1,
    const float* __restrict__ w2,    const float* __restrict__ b2,
    const float* __restrict__ ln2_g, const float* __restrict__ ln2_b,
    const float* __restrict__ pe2,
    int nbat,
    float* __restrict__ out)
{
    const int tid  = threadIdx.x;
    const int lane = tid & 63;
    const int c    = lane & 15;
    const int g    = lane >> 4;
    const int wgid = blockIdx.x * WPB + (tid >> 6);
    const float4v zero4 = {0.f, 0.f, 0.f, 0.f};

    // ---- per-lane weight fragments (loaded once per wave) ----
    half4v wprojF, wqF, wkF, wvF, woF;
    {
        float4v t;
        if (g < 2) {
            const float* p = &w_proj[c * 8 + 4 * g];
            t = (float4v){p[0], p[1], p[2], p[3]};
        } else t = zero4;
        #pragma unroll
        for (int j = 0; j < 4; ++j) wprojF[j] = (_Float16)t[j];
        const float* pq = &w_in[c * 16 + 4 * g];
        #pragma unroll
        for (int j = 0; j < 4; ++j) wqF[j] = (_Float16)(pq[j] * 0.25f);
        const float* pk = &w_in[(16 + c) * 16 + 4 * g];
        #pragma unroll
        for (int j = 0; j < 4; ++j) wkF[j] = (_Float16)pk[j];
        const float* pv = &w_in[(32 + c) * 16 + 4 * g];
        #pragma unroll
        for (int j = 0; j < 4; ++j) wvF[j] = (_Float16)pv[j];
        const float* po = &w_out[c * 16 + 4 * g];
        #pragma unroll
        for (int j = 0; j < 4; ++j) woF[j] = (_Float16)po[j];
    }
    float4v bq4, bk4, bo4, g14, b14, g24, b24v, w14, w24, bb24;
    #pragma unroll
    for (int j = 0; j < 4; ++j) {
        const int f = 4 * g + j;
        bq4[j] = b_in[f] * 0.25f; bk4[j] = b_in[16 + f];
        bo4[j] = b_out[f];
        g14[j] = ln1_g[f]; b14[j] = ln1_b[f];
        g24[j] = ln2_g[f]; b24v[j] = ln2_b[f];
        w14[j] = w1[f]; w24[j] = w2[f]; bb24[j] = b2[f];
    }
    const float bvc = b_in[32 + c];
    const float b1v = b1[0];

    for (int bi = 0; bi < NB; ++bi) {
        const int batch = wgid * NB + bi;
        if (batch >= nbat) break;
        const float* xrow = x + (size_t)batch * LIN;

        // ---- phase 1: h tiles via MFMA (K=16, patches zero-padded 8->16) ----
        half4v hf[9];
        #pragma unroll
        for (int st = 0; st < 9; ++st) {
            const int s = st * 16 + c;
            half4v xf;
            if (st < 8) {
                if (g < 2) {
                    const float* xp = &xrow[s * 8 + 4 * g];
                    #pragma unroll
                    for (int j = 0; j < 4; ++j) xf[j] = (_Float16)xp[j];
                } else {
                    #pragma unroll
                    for (int j = 0; j < 4; ++j) xf[j] = (_Float16)0.f;
                }
            } else {
                #pragma unroll
                for (int j = 0; j < 4; ++j) {
                    const int idx = s * 8 + 4 * g + j;
                    const float v = (g < 2 && idx < LIN) ? xrow[idx] : 0.f;
                    xf[j] = (_Float16)v;
                }
            }
            float4v d = __builtin_amdgcn_mfma_f32_16x16x16f16(wprojF, xf, zero4, 0, 0, 0);
            const float* pp = &pe2[s * 16 + 4 * g];
            #pragma unroll
            for (int j = 0; j < 4; ++j) hf[st][j] = (_Float16)(d[j] + pp[j]);
        }

        // ---- phase 2: q,k in-lane; V^T by operand swap. All registers. ----
        half4v qf[9], kf[9], vf[9];
        #pragma unroll
        for (int st = 0; st < 9; ++st) {
            float4v dq = __builtin_amdgcn_mfma_f32_16x16x16f16(wqF, hf[st], zero4, 0, 0, 0);
            float4v dk = __builtin_amdgcn_mfma_f32_16x16x16f16(wkF, hf[st], zero4, 0, 0, 0);
            float4v dv = __builtin_amdgcn_mfma_f32_16x16x16f16(hf[st], wvF, zero4, 0, 0, 0);
            #pragma unroll
            for (int j = 0; j < 4; ++j) {
                qf[st][j] = (_Float16)(dq[j] + bq4[j]);
                kf[st][j] = (_Float16)(dk[j] + bk4[j]);
                vf[st][j] = (_Float16)(dv[j] + bvc);
            }
        }

        // ---- phase 3: full-row softmax + fused epilogue, 9 q-tiles ----
        float accm[4] = {0.f, 0.f, 0.f, 0.f};
        #pragma unroll
        for (int ti = 0; ti < 9; ++ti) {
            float4v s4[9];
            #pragma unroll
            for (int kt = 0; kt < 9; ++kt)
                s4[kt] = __builtin_amdgcn_mfma_f32_16x16x16f16(kf[kt], qf[ti], zero4, 0, 0, 0);
            s4[8][2] = -1e30f; s4[8][3] = -1e30f;
            if (g > 0) { s4[8][0] = -1e30f; s4[8][1] = -1e30f; }
            float m = fmaxf(fmaxf(s4[0][0], s4[0][1]), fmaxf(s4[0][2], s4[0][3]));
            #pragma unroll
            for (int kt = 1; kt < 9; ++kt)
                m = fmaxf(m, fmaxf(fmaxf(s4[kt][0], s4[kt][1]), fmaxf(s4[kt][2], s4[kt][3])));
            m = fmaxf(m, __shfl_xor(m, 16));
            m = fmaxf(m, __shfl_xor(m, 32));
            half4v pf[9];
            float l = 0.f;
            #pragma unroll
            for (int kt = 0; kt < 9; ++kt) {
                const float p0 = __expf(s4[kt][0] - m), p1 = __expf(s4[kt][1] - m);
                const float p2 = __expf(s4[kt][2] - m), p3 = __expf(s4[kt][3] - m);
                l += (p0 + p1) + (p2 + p3);
                pf[kt] = {(_Float16)p0, (_Float16)p1, (_Float16)p2, (_Float16)p3};
            }
            l += __shfl_xor(l, 16);
            l += __shfl_xor(l, 32);
            float4v Oa = zero4, Ob = zero4;
            #pragma unroll
            for (int kt = 0; kt < 9; kt += 2)
                Oa = __builtin_amdgcn_mfma_f32_16x16x16f16(vf[kt], pf[kt], Oa, 0, 0, 0);
            #pragma unroll
            for (int kt = 1; kt < 9; kt += 2)
                Ob = __builtin_amdgcn_mfma_f32_16x16x16f16(vf[kt], pf[kt], Ob, 0, 0, 0);
            const float inv = 1.0f / l;
            half4v cf;
            #pragma unroll
            for (int j = 0; j < 4; ++j) cf[j] = (_Float16)((Oa[j] + Ob[j]) * inv);
            float4v AO = __builtin_amdgcn_mfma_f32_16x16x16f16(woF, cf, zero4, 0, 0, 0);
            float h2[4], h3[4];
            #pragma unroll
            for (int j = 0; j < 4; ++j) h2[j] = (float)hf[ti][j] + AO[j] + bo4[j];
            float s1 = (h2[0] + h2[1]) + (h2[2] + h2[3]);
            s1 += __shfl_xor(s1, 16); s1 += __shfl_xor(s1, 32);
            const float mean = s1 * 0.0625f;
            float vv = 0.f;
            #pragma unroll
            for (int j = 0; j < 4; ++j) { const float d = h2[j] - mean; vv += d * d; }
            vv += __shfl_xor(vv, 16); vv += __shfl_xor(vv, 32);
            const float rstd = rsqrtf(vv * 0.0625f + 1e-5f);
            #pragma unroll
            for (int j = 0; j < 4; ++j)
                h2[j] = (h2[j] - mean) * rstd * g14[j] + b14[j];
            float fa = h2[0] * w14[0] + h2[1] * w14[1] + h2[2] * w14[2] + h2[3] * w14[3];
            fa += __shfl_xor(fa, 16); fa += __shfl_xor(fa, 32);
            const float ffa = fmaxf(fa + b1v, 0.f);
            #pragma unroll
            for (int j = 0; j < 4; ++j) h3[j] = h2[j] + ffa * w24[j] + bb24[j];
            float s2 = (h3[0] + h3[1]) + (h3[2] + h3[3]);
            s2 += __shfl_xor(s2, 16); s2 += __shfl_xor(s2, 32);
            const float mean2 = s2 * 0.0625f;
            float v2 = 0.f;
            #pragma unroll
            for (int j = 0; j < 4; ++j) { const float d = h3[j] - mean2; v2 += d * d; }
            v2 += __shfl_xor(v2, 16); v2 += __shfl_xor(v2, 32);
            const float rstd2 = rsqrtf(v2 * 0.0625f + 1e-5f);
            if (ti * 16 + c < SEQ) {
                #pragma unroll
                for (int j = 0; j < 4; ++j)
                    accm[j] += (h3[j] - mean2) * rstd2 * g24[j] + b24v[j];
            }
        }

        // ---- mean over rows: reduce across the 16 c-lanes; store from c==0 ----
        #pragma unroll
        for (int off = 1; off < 16; off <<= 1) {
            #pragma unroll
            for (int j = 0; j < 4; ++j) accm[j] += __shfl_xor(accm[j], off);
        }
        if (c == 0) {
            float* op = &out[(size_t)batch * 16 + 4 * g];
            #pragma unroll
            for (int j = 0; j < 4; ++j) op[j] = accm[j] * (1.0f / 130.0f);
        }
    }
}

extern "C" void kernel_launch(void* const* d_in, const int* in_sizes, int n_in,
                              void* d_out, int out_size, void* d_ws, size_t ws_size,
                              hipStream_t stream) {
    const float* x      = (const float*)d_in[0];
    const float* w_proj = (const float*)d_in[1];
    const float* b_proj = (const float*)d_in[2];
    const float* w_in   = (const float*)d_in[3];
    const float* b_in   = (const float*)d_in[4];
    const float* w_out  = (const float*)d_in[5];
    const float* b_out  = (const float*)d_in[6];
    const float* ln1_g  = (const float*)d_in[7];
    const float* ln1_b  = (const float*)d_in[8];
    const float* w1     = (const float*)d_in[9];
    const float* b1     = (const float*)d_in[10];
    const float* w2     = (const float*)d_in[11];
    const float* b2     = (const float*)d_in[12];
    const float* ln2_g  = (const float*)d_in[13];
    const float* ln2_b  = (const float*)d_in[14];

    float* pe2 = (float*)d_ws;
    pe_kernel<<<9, 256, 0, stream>>>(b_proj, pe2);

    int B = in_sizes[0] / LIN;
    int grid = (B + WPB * NB - 1) / (WPB * NB);
    st_kernel<<<grid, 256, 0, stream>>>(x, w_proj, w_in, b_in,
                                        w_out, b_out, ln1_g, ln1_b,
                                        w1, b1, w2, b2, ln2_g, ln2_b,
                                        pe2, B, (float*)d_out);
}